// Round 11
// baseline (96.410 us; speedup 1.0000x reference)
//
#include <hip/hip_runtime.h>
#include <hip/hip_bf16.h>
#include <math.h>

// Problem constants
#define NTOK 2048
#define CDIM 1024
#define NHEAD 16
#define HDIM 64
// frame id = token >> 8 (8 frames of 256 tokens)

typedef __attribute__((ext_vector_type(8))) short bf16x8;
typedef __attribute__((ext_vector_type(4))) short bf16x4;
typedef __attribute__((ext_vector_type(4))) float f32x4;
typedef __attribute__((ext_vector_type(4))) unsigned int u32x4;

// ---------------------------------------------------------------------------
// helpers
// ---------------------------------------------------------------------------
__device__ inline unsigned short bf16_rn(float f) {
    unsigned int u = __float_as_uint(f);
    u += 0x7FFFu + ((u >> 16) & 1u);
    return (unsigned short)(u >> 16);
}

template <int N> __device__ inline void waitcnt_vm() {
    if constexpr (N == 0) asm volatile("s_waitcnt vmcnt(0)" ::: "memory");
    else if constexpr (N == 2) asm volatile("s_waitcnt vmcnt(2)" ::: "memory");
    else if constexpr (N == 3) asm volatile("s_waitcnt vmcnt(3)" ::: "memory");
    else if constexpr (N == 4) asm volatile("s_waitcnt vmcnt(4)" ::: "memory");
}

__device__ inline void gload16(const void* g, void* l) {
    __builtin_amdgcn_global_load_lds((const __attribute__((address_space(1))) void*)g,
                                     (__attribute__((address_space(3))) void*)l,
                                     16, 0, 0);
}

// One dispatch: convert x, Wqkv, Wproj to plain bf16.
__global__ __launch_bounds__(256) void conv3(const float* __restrict__ s0, unsigned short* __restrict__ h0, int nb0,
                                             const float* __restrict__ s1, unsigned short* __restrict__ h1, int nb1,
                                             const float* __restrict__ s2, unsigned short* __restrict__ h2) {
    int b = blockIdx.x;
    const float* s;
    unsigned short* hh;
    if (b < nb0) { s = s0; hh = h0; }
    else if (b < nb0 + nb1) { s = s1; hh = h1; b -= nb0; }
    else { s = s2; hh = h2; b -= nb0 + nb1; }
    const int i = b * 256 + threadIdx.x;
    float4 v = ((const float4*)s)[i];
    ushort4 h;
    h.x = bf16_rn(v.x); h.y = bf16_rn(v.y); h.z = bf16_rn(v.z); h.w = bf16_rn(v.w);
    ((ushort4*)hh)[i] = h;
}

// ---------------------------------------------------------------------------
// MFMA GEMM, 1-term bf16, counted-vmcnt double buffer. 4 waves (2x2).
// MODE 1 (QKV): epilogue writes attention-ready bf16: q (scaled 0.125,
//   swizzled), K (swizzled), V^T (swizzled).
// MODE 2 (PROJ): f32 out + bias.
// ---------------------------------------------------------------------------
template <int BM, int BN, int M, int N, int K, int MODE>
__global__ __launch_bounds__(256) void gemm_mfma(const unsigned short* __restrict__ Ah,
                                                 const unsigned short* __restrict__ Bh,
                                                 const float* __restrict__ bias,
                                                 float* __restrict__ C,
                                                 unsigned short* __restrict__ qgp,
                                                 unsigned short* __restrict__ kgp,
                                                 unsigned short* __restrict__ vtg) {
    constexpr int FM = BM / 32;
    constexpr int FN = BN / 32;
    constexpr int ASZ = BM * 32;
    constexpr int BSZ = BN * 32;
    constexpr int BUF = ASZ + BSZ;
    __shared__ unsigned short lds[2 * BUF];

    const int tid = threadIdx.x;
    const int lane = tid & 63;
    const int w = tid >> 6;
    const int m0 = blockIdx.y * BM;
    const int n0 = blockIdx.x * BN;
    const int wave_m = (w >> 1) * (BM / 2);
    const int wave_n = (w & 1) * (BN / 2);
    const int lr = lane & 15;
    const int kg_ = lane >> 4;
    const int srow = tid >> 2;
    const int scol = (tid & 3) * 8;

    const size_t aRow = (size_t)(m0 + srow) * K + scol;
    const size_t bRow = (size_t)(n0 + (srow & (BN - 1))) * K + scol;

    f32x4 acc[FM][FN];
#pragma unroll
    for (int i = 0; i < FM; ++i)
#pragma unroll
        for (int j = 0; j < FN; ++j) acc[i][j] = {0.f, 0.f, 0.f, 0.f};

    auto stage = [&](int buf, int k0) {
        unsigned short* bb = lds + buf * BUF;
#pragma unroll
        for (int j = 0; j < BM / 64; ++j) {
            const size_t ga = aRow + (size_t)j * 64 * K + k0;
            gload16(Ah + ga, bb + (srow + j * 64) * 32 + scol);
        }
        if constexpr (BN >= 64) {
#pragma unroll
            for (int j = 0; j < (BN + 63) / 64; ++j) {
                const size_t gb = bRow + (size_t)j * 64 * K + k0;
                gload16(Bh + gb, bb + ASZ + ((srow & (BN - 1)) + j * 64) * 32 + scol);
            }
        }
    };

    stage(0, 0);
    constexpr int NL = BM / 64 + (BN + 63) / 64;
    constexpr int NT = K / 32;
    for (int t = 0; t < NT; ++t) {
        const int cur = t & 1;
        if (t + 1 < NT) {
            stage(cur ^ 1, (t + 1) * 32);
            waitcnt_vm<NL>();
        } else {
            waitcnt_vm<0>();
        }
        __builtin_amdgcn_s_barrier();

        const unsigned short* bb = lds + cur * BUF;
        bf16x8 ah[FM], bh[FN];
#pragma unroll
        for (int f = 0; f < FM; ++f)
            ah[f] = *(const bf16x8*)&bb[(wave_m + f * 16 + lr) * 32 + kg_ * 8];
#pragma unroll
        for (int f = 0; f < FN; ++f)
            bh[f] = *(const bf16x8*)&bb[ASZ + (wave_n + f * 16 + lr) * 32 + kg_ * 8];
        __builtin_amdgcn_s_setprio(1);
#pragma unroll
        for (int fm = 0; fm < FM; ++fm)
#pragma unroll
            for (int fn = 0; fn < FN; ++fn)
                acc[fm][fn] = __builtin_amdgcn_mfma_f32_16x16x32_bf16(ah[fm], bh[fn], acc[fm][fn], 0, 0, 0);
        __builtin_amdgcn_s_setprio(0);
        asm volatile("" ::: "memory");
        __builtin_amdgcn_s_barrier();
    }

    // epilogue: C/D layout col=lane&15, row=(lane>>4)*4+reg  [m89-verified]
    if constexpr (MODE == 2) {
        float bv[FN];
#pragma unroll
        for (int fn = 0; fn < FN; ++fn) bv[fn] = bias[n0 + wave_n + fn * 16 + lr];
#pragma unroll
        for (int fm = 0; fm < FM; ++fm) {
            const int row0 = m0 + wave_m + fm * 16 + kg_ * 4;
#pragma unroll
            for (int fn = 0; fn < FN; ++fn) {
                const int col = n0 + wave_n + fn * 16 + lr;
#pragma unroll
                for (int r = 0; r < 4; ++r)
                    C[(size_t)(row0 + r) * N + col] = acc[fm][fn][r] + bv[fn];
            }
        }
    } else {
        const int reg = n0 >> 10;  // 0=q, 1=k, 2=v (uniform per block)
#pragma unroll
        for (int fn = 0; fn < FN; ++fn) {
            const int col = n0 + wave_n + fn * 16 + lr;
            const int head = (col >> 6) & 15;
            const int d = col & 63;
            const float bv = bias[col];
#pragma unroll
            for (int fm = 0; fm < FM; ++fm) {
                const int row0 = m0 + wave_m + fm * 16 + kg_ * 4;
                if (reg == 2) {
                    // V^T [h][d][tok ^ ((d&7)<<3)]
                    ushort4 pk;
                    pk.x = bf16_rn(acc[fm][fn][0] + bv);
                    pk.y = bf16_rn(acc[fm][fn][1] + bv);
                    pk.z = bf16_rn(acc[fm][fn][2] + bv);
                    pk.w = bf16_rn(acc[fm][fn][3] + bv);
                    const size_t idx = (size_t)(head * 64 + d) * 2048 + (size_t)(row0 ^ ((d & 7) << 3));
                    *(ushort4*)&vtg[idx] = pk;
                } else {
                    // q (scaled 0.125) / K plain bf16 [h][tok][d ^ ((tok&7)<<3)]
                    const float sc = (reg == 0) ? 0.125f : 1.0f;
                    unsigned short* dp = (reg == 0) ? qgp : kgp;
#pragma unroll
                    for (int r = 0; r < 4; ++r) {
                        const int tok = row0 + r;
                        const size_t idx = ((size_t)head * 2048 + tok) * 64 + (d ^ ((tok & 7) << 3));
                        dp[idx] = bf16_rn((acc[fm][fn][r] + bv) * sc);
                    }
                }
            }
        }
    }
}

// ---------------------------------------------------------------------------
// MFMA sparse flash attention — NO LDS STAGING, no barriers in the loop.
// K/V are L2-resident (512 KB/head; 2 heads per XCD via swizzle). Block =
// (head, 16 q-rows) x 4 waves; wave w processes tiles w, w+4, ... of the
// allowed list with private (m,l,O); one end-of-kernel LDS merge.
// Grid 2048 blocks x 256 threads.
// ---------------------------------------------------------------------------
__global__ __launch_bounds__(256) void attn_mfma(const unsigned short* __restrict__ qgp,
                                                 const unsigned short* __restrict__ kgp,
                                                 const unsigned short* __restrict__ vtg,
                                                 const float* __restrict__ frame_bias,
                                                 const int* __restrict__ adj,
                                                 const int* __restrict__ is_hub,
                                                 unsigned short* __restrict__ ath) {
    __shared__ float sMrg[3][64][18];   // 13.5 KB: partials of waves 1..3
    __shared__ int sList[32];
    __shared__ float sFB[8];
    __shared__ unsigned long long sHub[32];
    __shared__ int sNT;

    // XCD decode: bid&7 = XCD, each XCD owns heads {2r, 2r+1}; 2048 blocks
    const int bid = blockIdx.x;
    const int r8 = bid & 7, tt = bid >> 3;      // tt in [0,256)
    const int q16 = tt & 127, hb = tt >> 7;
    const int h = r8 * 2 + hb;
    const int q0 = q16 * 16;

    const int tid = threadIdx.x;
    const int lane = tid & 63;
    const int w = tid >> 6;        // 0..3 (KV-split part)
    const int lr = lane & 15;
    const int kg = lane >> 4;
    const int fi = q0 >> 8;

    // ---- Q fragments (plain bf16, pre-swizzled global layout) ----
    const int qgl = q0 + lr;                 // this lane's global token
    const unsigned short* qb_ = qgp + ((size_t)h * 2048 + qgl) * 64;
    const int Xq = (qgl & 7) << 3;
    bf16x8 qh[2];
#pragma unroll
    for (int dc = 0; dc < 2; ++dc)
        qh[dc] = *(const bf16x8*)&qb_[(dc * 32 + kg * 8) ^ Xq];
    const bool hq = is_hub[qgl] != 0;

    // ---- prologue tables ----
#pragma unroll
    for (int i = 0; i < 8; ++i) {
        const int t2 = w * 8 + i;
        unsigned long long mb = __ballot(is_hub[t2 * 64 + lane] != 0);
        if (lane == 0) sHub[t2] = mb;
    }
    if (tid < 8) sFB[tid] = frame_bias[fi * 8 + tid];
    if (w == 0) {
        const bool ok = (lane < 32) && (adj[fi * 8 + ((lane & 31) >> 2)] != 0);
        const unsigned long long am = __ballot(ok);
        if (lane == 0) {
            int c = 0;
#pragma unroll 1
            for (int t2 = 0; t2 < 32; ++t2)
                if ((am >> t2) & 1ull) sList[c++] = t2;
            sNT = c;
        }
    }
    __syncthreads();
    const int nt = sNT;   // >= 4 always (diagonal of adj)

    const unsigned short* kbase = kgp + (size_t)h * 2048 * 64;
    const unsigned short* vbase = vtg + (size_t)h * 64 * 2048;
    const int Xl = (lr & 7) << 3;   // row-dependent XOR (rows stride 16 -> only lr matters)

    float m_i = -INFINITY, l_i = 0.f;
    f32x4 oacc[4];
#pragma unroll
    for (int fd = 0; fd < 4; ++fd) oacc[fd] = {0.f, 0.f, 0.f, 0.f};

#pragma unroll 1
    for (int i = w; i < nt; i += 4) {
        const int tile = sList[i];
        const int n0s = tile * 64;
        const int fj = tile >> 2;
        const bool same = (fj == fi);
        const float biasv = sFB[fj];
        const unsigned long long hubmask = sHub[tile];

        // ---- K fragments direct from global (L2-hit, 8 x 16B) ----
        bf16x8 kf[4][2];
#pragma unroll
        for (int fk = 0; fk < 4; ++fk)
#pragma unroll
            for (int dc = 0; dc < 2; ++dc)
                kf[fk][dc] = *(const bf16x8*)&kbase[(size_t)(n0s + fk * 16 + lr) * 64 +
                                                   ((dc * 32 + kg * 8) ^ Xl)];
        // ---- V fragments direct from global (16 x 8B) ----
        bf16x4 vf[2][4][2];
#pragma unroll
        for (int c = 0; c < 2; ++c)
#pragma unroll
            for (int fd = 0; fd < 4; ++fd) {
                const size_t vb = (size_t)(fd * 16 + lr) * 2048 + n0s;
                vf[c][fd][0] = *(const bf16x4*)&vbase[vb + ((c * 32 + kg * 4) ^ Xl)];
                vf[c][fd][1] = *(const bf16x4*)&vbase[vb + ((c * 32 + 16 + kg * 4) ^ Xl)];
            }

        // ---- S^T = K . Q^T ----
        f32x4 sacc[4];
#pragma unroll
        for (int fk = 0; fk < 4; ++fk) sacc[fk] = {0.f, 0.f, 0.f, 0.f};
        __builtin_amdgcn_s_setprio(1);
#pragma unroll
        for (int fk = 0; fk < 4; ++fk)
#pragma unroll
            for (int dc = 0; dc < 2; ++dc)
                sacc[fk] = __builtin_amdgcn_mfma_f32_16x16x32_bf16(kf[fk][dc], qh[dc], sacc[fk], 0, 0, 0);
        __builtin_amdgcn_s_setprio(0);

        // ---- mask + bias + online softmax (lane owns 16 scores of its q) ----
        float sv[4][4];
        float rmax = -INFINITY;
#pragma unroll
        for (int fk = 0; fk < 4; ++fk)
#pragma unroll
            for (int r = 0; r < 4; ++r) {
                float val = sacc[fk][r] + biasv;
                if (!same) {
                    const int k = fk * 16 + kg * 4 + r;
                    if (hq || ((hubmask >> k) & 1ull)) val = -INFINITY;
                }
                sv[fk][r] = val;
                rmax = fmaxf(rmax, val);
            }
        rmax = fmaxf(rmax, __shfl_xor(rmax, 16));
        rmax = fmaxf(rmax, __shfl_xor(rmax, 32));

        const float mn = fmaxf(m_i, rmax);
        const float alpha = (mn == -INFINITY) ? 1.f : __expf(m_i - mn);
        m_i = mn;

        float p4[4][4];
        float psum = 0.f;
#pragma unroll
        for (int fk = 0; fk < 4; ++fk)
#pragma unroll
            for (int r = 0; r < 4; ++r) {
                const float pv = (sv[fk][r] == -INFINITY) ? 0.f : __expf(sv[fk][r] - mn);
                p4[fk][r] = pv;
                psum += pv;
            }
        psum += __shfl_xor(psum, 16);
        psum += __shfl_xor(psum, 32);
        l_i = l_i * alpha + psum;
#pragma unroll
        for (int fd = 0; fd < 4; ++fd) {
            oacc[fd][0] *= alpha; oacc[fd][1] *= alpha;
            oacc[fd][2] *= alpha; oacc[fd][3] *= alpha;
        }

        // ---- pack P, O^T += V^T . P^T (k-slot permuted) ----
        unsigned int pc[4][2];
#pragma unroll
        for (int fk = 0; fk < 4; ++fk)
#pragma unroll
            for (int rp = 0; rp < 2; ++rp)
                pc[fk][rp] = (unsigned int)bf16_rn(p4[fk][2 * rp]) |
                             ((unsigned int)bf16_rn(p4[fk][2 * rp + 1]) << 16);
        __builtin_amdgcn_s_setprio(1);
#pragma unroll
        for (int c = 0; c < 2; ++c) {
            u32x4 pw = {pc[2 * c][0], pc[2 * c][1], pc[2 * c + 1][0], pc[2 * c + 1][1]};
            bf16x8 pbv = __builtin_bit_cast(bf16x8, pw);
#pragma unroll
            for (int fd = 0; fd < 4; ++fd) {
                bf16x8 va = __builtin_shufflevector(vf[c][fd][0], vf[c][fd][1], 0, 1, 2, 3, 4, 5, 6, 7);
                oacc[fd] = __builtin_amdgcn_mfma_f32_16x16x32_bf16(va, pbv, oacc[fd], 0, 0, 0);
            }
        }
        __builtin_amdgcn_s_setprio(0);
    }

    // ---- merge 4 wave-partials via LDS ----
    __syncthreads();
    if (w > 0) {
        float* mp = &sMrg[w - 1][lane][0];
        mp[0] = m_i;
        mp[1] = l_i;
#pragma unroll
        for (int fd = 0; fd < 4; ++fd)
#pragma unroll
            for (int r = 0; r < 4; ++r) mp[2 + fd * 4 + r] = oacc[fd][r];
    }
    __syncthreads();
    if (w == 0) {
        float m = m_i;
#pragma unroll
        for (int j = 0; j < 3; ++j) m = fmaxf(m, sMrg[j][lane][0]);
        const float a0 = (m_i == -INFINITY) ? 0.f : __expf(m_i - m);
        float lsum = l_i * a0;
        float ov[4][4];
#pragma unroll
        for (int fd = 0; fd < 4; ++fd)
#pragma unroll
            for (int r = 0; r < 4; ++r) ov[fd][r] = oacc[fd][r] * a0;
#pragma unroll
        for (int j = 0; j < 3; ++j) {
            const float mj = sMrg[j][lane][0];
            const float aj = (mj == -INFINITY) ? 0.f : __expf(mj - m);
            lsum += sMrg[j][lane][1] * aj;
#pragma unroll
            for (int fd = 0; fd < 4; ++fd)
#pragma unroll
                for (int r = 0; r < 4; ++r)
                    ov[fd][r] += sMrg[j][lane][2 + fd * 4 + r] * aj;
        }
        const float inv = 1.f / lsum;
#pragma unroll
        for (int fd = 0; fd < 4; ++fd) {
            ushort4 h4;
            h4.x = bf16_rn(ov[fd][0] * inv);
            h4.y = bf16_rn(ov[fd][1] * inv);
            h4.z = bf16_rn(ov[fd][2] * inv);
            h4.w = bf16_rn(ov[fd][3] * inv);
            const size_t idx = (size_t)qgl * CDIM + h * 64 + fd * 16 + kg * 4;
            *(ushort4*)&ath[idx] = h4;
        }
    }
}

// ---------------------------------------------------------------------------
extern "C" void kernel_launch(void* const* d_in, const int* in_sizes, int n_in,
                              void* d_out, int out_size, void* d_ws, size_t ws_size,
                              hipStream_t stream) {
    const float* x          = (const float*)d_in[0];
    const float* Wqkv       = (const float*)d_in[1];
    const float* bqkv       = (const float*)d_in[2];
    const float* Wproj      = (const float*)d_in[3];
    const float* bproj      = (const float*)d_in[4];
    const float* frame_bias = (const float*)d_in[5];
    const int*   adj        = (const int*)d_in[6];
    const int*   is_hub     = (const int*)d_in[8];
    float* out = (float*)d_out;

    char* ws = (char*)d_ws;
    size_t off = 0;
    auto alloc_us = [&](size_t n) { unsigned short* p = (unsigned short*)(ws + off); off += n * 2; return p; };
    unsigned short* qg  = alloc_us((size_t)NHEAD * NTOK * HDIM);
    unsigned short* kg  = alloc_us((size_t)NHEAD * NTOK * HDIM);
    unsigned short* vtg = alloc_us((size_t)NHEAD * HDIM * NTOK);
    unsigned short* xh  = alloc_us((size_t)NTOK * CDIM);
    unsigned short* wqh = alloc_us((size_t)3 * CDIM * CDIM);
    unsigned short* wph = alloc_us((size_t)CDIM * CDIM);
    unsigned short* ath = alloc_us((size_t)NTOK * CDIM);

    const int nb_x = (NTOK * CDIM / 4) / 256;
    const int nb_wq = (3 * CDIM * CDIM / 4) / 256;
    const int nb_wp = (CDIM * CDIM / 4) / 256;
    conv3<<<nb_x + nb_wq + nb_wp, 256, 0, stream>>>(x, xh, nb_x,
                                                    Wqkv, wqh, nb_wq,
                                                    Wproj, wph);

    // 1) QKV projection (1-term); epilogue emits attention-ready bf16 buffers
    gemm_mfma<64, 128, NTOK, 3 * CDIM, CDIM, 1>
        <<<dim3((3 * CDIM) / 128, NTOK / 64), 256, 0, stream>>>(
            xh, wqh, bqkv, nullptr, qg, kg, vtg);
    // 2) sparse attention (no-LDS, 4-way KV split, end-merge), writes bf16 att
    attn_mfma<<<2048, 256, 0, stream>>>(qg, kg, vtg,
                                        frame_bias, adj, is_hub, ath);
    // 3) output projection (1-term, BN=64 -> 512 blocks for 2 blocks/CU)
    gemm_mfma<64, 64, NTOK, CDIM, CDIM, 2>
        <<<dim3(CDIM / 64, NTOK / 64), 256, 0, stream>>>(
            ath, wph, bproj, out, nullptr, nullptr, nullptr);
}

// Round 12
// 73.021 us; speedup vs baseline: 1.3203x; 1.3203x over previous
//
#include <hip/hip_runtime.h>
#include <hip/hip_bf16.h>
#include <math.h>

// Problem constants
#define NTOK 2048
#define CDIM 1024
#define NHEAD 16
#define HDIM 64
// frame id = token >> 8 (8 frames of 256 tokens)

typedef __attribute__((ext_vector_type(8))) short bf16x8;
typedef __attribute__((ext_vector_type(4))) float f32x4;
typedef __attribute__((ext_vector_type(4))) unsigned int u32x4;

// ---------------------------------------------------------------------------
// helpers
// ---------------------------------------------------------------------------
__device__ inline unsigned short bf16_rn(float f) {
    unsigned int u = __float_as_uint(f);
    u += 0x7FFFu + ((u >> 16) & 1u);
    return (unsigned short)(u >> 16);
}

template <int N> __device__ inline void waitcnt_vm() {
    if constexpr (N == 0) asm volatile("s_waitcnt vmcnt(0)" ::: "memory");
    else if constexpr (N == 2) asm volatile("s_waitcnt vmcnt(2)" ::: "memory");
    else if constexpr (N == 3) asm volatile("s_waitcnt vmcnt(3)" ::: "memory");
}

__device__ inline void gload16(const void* g, void* l) {
    __builtin_amdgcn_global_load_lds((const __attribute__((address_space(1))) void*)g,
                                     (__attribute__((address_space(3))) void*)l,
                                     16, 0, 0);
}

// One dispatch: convert x, Wqkv, Wproj to plain bf16.
__global__ __launch_bounds__(256) void conv3(const float* __restrict__ s0, unsigned short* __restrict__ h0, int nb0,
                                             const float* __restrict__ s1, unsigned short* __restrict__ h1, int nb1,
                                             const float* __restrict__ s2, unsigned short* __restrict__ h2) {
    int b = blockIdx.x;
    const float* s;
    unsigned short* hh;
    if (b < nb0) { s = s0; hh = h0; }
    else if (b < nb0 + nb1) { s = s1; hh = h1; b -= nb0; }
    else { s = s2; hh = h2; b -= nb0 + nb1; }
    const int i = b * 256 + threadIdx.x;
    float4 v = ((const float4*)s)[i];
    ushort4 h;
    h.x = bf16_rn(v.x); h.y = bf16_rn(v.y); h.z = bf16_rn(v.z); h.w = bf16_rn(v.w);
    ((ushort4*)hh)[i] = h;
}

// ---------------------------------------------------------------------------
// MFMA GEMM, 1-term bf16, counted-vmcnt double buffer. 4 waves (2x2).
// MODE 1 (QKV): epilogue writes attention FRAGMENT-ORDERED bf16 buffers:
//   qf[h][q16][dc][lane][8]   (scaled 0.125)   lane = kg*16 + (tok&15)
//   kf[h][tile][fk][dc][lane][8]
//   vf[h][tile][c][fd][lane][8]                (element order matches PV A-op)
// MODE 2 (PROJ): f32 out + bias.
// ---------------------------------------------------------------------------
template <int BM, int BN, int M, int N, int K, int MODE>
__global__ __launch_bounds__(256) void gemm_mfma(const unsigned short* __restrict__ Ah,
                                                 const unsigned short* __restrict__ Bh,
                                                 const float* __restrict__ bias,
                                                 float* __restrict__ C,
                                                 unsigned short* __restrict__ qfb,
                                                 unsigned short* __restrict__ kfb,
                                                 unsigned short* __restrict__ vfb) {
    constexpr int FM = BM / 32;
    constexpr int FN = BN / 32;
    constexpr int ASZ = BM * 32;
    constexpr int BSZ = BN * 32;
    constexpr int BUF = ASZ + BSZ;
    __shared__ unsigned short lds[2 * BUF];

    const int tid = threadIdx.x;
    const int lane = tid & 63;
    const int w = tid >> 6;
    const int m0 = blockIdx.y * BM;
    const int n0 = blockIdx.x * BN;
    const int wave_m = (w >> 1) * (BM / 2);
    const int wave_n = (w & 1) * (BN / 2);
    const int lr = lane & 15;
    const int kg_ = lane >> 4;
    const int srow = tid >> 2;
    const int scol = (tid & 3) * 8;

    const size_t aRow = (size_t)(m0 + srow) * K + scol;
    const size_t bRow = (size_t)(n0 + (srow & (BN - 1))) * K + scol;

    f32x4 acc[FM][FN];
#pragma unroll
    for (int i = 0; i < FM; ++i)
#pragma unroll
        for (int j = 0; j < FN; ++j) acc[i][j] = {0.f, 0.f, 0.f, 0.f};

    auto stage = [&](int buf, int k0) {
        unsigned short* bb = lds + buf * BUF;
#pragma unroll
        for (int j = 0; j < BM / 64; ++j) {
            const size_t ga = aRow + (size_t)j * 64 * K + k0;
            gload16(Ah + ga, bb + (srow + j * 64) * 32 + scol);
        }
#pragma unroll
        for (int j = 0; j < (BN + 63) / 64; ++j) {
            const size_t gb = bRow + (size_t)j * 64 * K + k0;
            gload16(Bh + gb, bb + ASZ + ((srow & (BN - 1)) + j * 64) * 32 + scol);
        }
    };

    stage(0, 0);
    constexpr int NL = BM / 64 + (BN + 63) / 64;
    constexpr int NT = K / 32;
    for (int t = 0; t < NT; ++t) {
        const int cur = t & 1;
        if (t + 1 < NT) {
            stage(cur ^ 1, (t + 1) * 32);
            waitcnt_vm<NL>();
        } else {
            waitcnt_vm<0>();
        }
        __builtin_amdgcn_s_barrier();

        const unsigned short* bb = lds + cur * BUF;
        bf16x8 ah[FM], bh[FN];
#pragma unroll
        for (int f = 0; f < FM; ++f)
            ah[f] = *(const bf16x8*)&bb[(wave_m + f * 16 + lr) * 32 + kg_ * 8];
#pragma unroll
        for (int f = 0; f < FN; ++f)
            bh[f] = *(const bf16x8*)&bb[ASZ + (wave_n + f * 16 + lr) * 32 + kg_ * 8];
        __builtin_amdgcn_s_setprio(1);
#pragma unroll
        for (int fm = 0; fm < FM; ++fm)
#pragma unroll
            for (int fn = 0; fn < FN; ++fn)
                acc[fm][fn] = __builtin_amdgcn_mfma_f32_16x16x32_bf16(ah[fm], bh[fn], acc[fm][fn], 0, 0, 0);
        __builtin_amdgcn_s_setprio(0);
        asm volatile("" ::: "memory");
        __builtin_amdgcn_s_barrier();
    }

    // epilogue: C/D layout col=lane&15, row=(lane>>4)*4+reg  [m89-verified]
    if constexpr (MODE == 2) {
        float bv[FN];
#pragma unroll
        for (int fn = 0; fn < FN; ++fn) bv[fn] = bias[n0 + wave_n + fn * 16 + lr];
#pragma unroll
        for (int fm = 0; fm < FM; ++fm) {
            const int row0 = m0 + wave_m + fm * 16 + kg_ * 4;
#pragma unroll
            for (int fn = 0; fn < FN; ++fn) {
                const int col = n0 + wave_n + fn * 16 + lr;
#pragma unroll
                for (int r = 0; r < 4; ++r)
                    C[(size_t)(row0 + r) * N + col] = acc[fm][fn][r] + bv[fn];
            }
        }
    } else {
        const int reg = n0 >> 10;  // 0=q, 1=k, 2=v (uniform per block)
#pragma unroll
        for (int fn = 0; fn < FN; ++fn) {
            const int col = n0 + wave_n + fn * 16 + lr;
            const int head = (col >> 6) & 15;
            const int d = col & 63;
            const float bv = bias[col];
#pragma unroll
            for (int fm = 0; fm < FM; ++fm) {
                const int row0 = m0 + wave_m + fm * 16 + kg_ * 4;  // tok base (mult of 4)
                if (reg == 2) {
                    // vf[h][tile][c][fd][lane][8]; tok&3 == e-low -> ushort4 at e=hi*4
                    const int tok = row0;
                    const int tile = tok >> 6;
                    const int t6 = tok & 63;
                    const int c = t6 >> 5;
                    const int t5 = t6 & 31;
                    const int hi = (t5 >> 4) & 1;
                    const int kgv = (t5 >> 2) & 3;
                    const int fd = d >> 4;
                    const int lrv = d & 15;
                    ushort4 pk;
                    pk.x = bf16_rn(acc[fm][fn][0] + bv);
                    pk.y = bf16_rn(acc[fm][fn][1] + bv);
                    pk.z = bf16_rn(acc[fm][fn][2] + bv);
                    pk.w = bf16_rn(acc[fm][fn][3] + bv);
                    const size_t idx = (((size_t)((head * 32 + tile) * 2 + c) * 4 + fd) * 64 +
                                        (kgv * 16 + lrv)) * 8 + hi * 4;
                    *(ushort4*)&vfb[idx] = pk;
                } else if (reg == 1) {
                    // kf[h][tile][fk][dc][lane][8]
                    const int dc = d >> 5;
                    const int kgq = (d >> 3) & 3;
                    const int e = d & 7;
#pragma unroll
                    for (int r = 0; r < 4; ++r) {
                        const int tok = row0 + r;
                        const int tile = tok >> 6;
                        const int fk = (tok >> 4) & 3;
                        const int lrk = tok & 15;
                        const size_t idx = (((size_t)((head * 32 + tile) * 4 + fk) * 2 + dc) * 64 +
                                            (kgq * 16 + lrk)) * 8 + e;
                        kfb[idx] = bf16_rn(acc[fm][fn][r] + bv);
                    }
                } else {
                    // qf[h][q16][dc][lane][8], scaled 0.125
                    const int dc = d >> 5;
                    const int kgq = (d >> 3) & 3;
                    const int e = d & 7;
#pragma unroll
                    for (int r = 0; r < 4; ++r) {
                        const int tok = row0 + r;
                        const int q16i = tok >> 4;
                        const int lrk = tok & 15;
                        const size_t idx = (((size_t)(head * 128 + q16i) * 2 + dc) * 64 +
                                            (kgq * 16 + lrk)) * 8 + e;
                        qfb[idx] = bf16_rn((acc[fm][fn][r] + bv) * 0.125f);
                    }
                }
            }
        }
    }
}

// ---------------------------------------------------------------------------
// MFMA sparse flash attention — fragment-ordered global K/V/Q, COALESCED
// direct loads, NO LDS staging, NO barriers in the loop.
// Block = 128 threads = 2 waves = the two KV-halves of one (head, 16-q group);
// each wave owns tiles i = half, half+2, ... with private (m,l,O); one LDS
// merge at the end. 2048 blocks -> 4096 waves -> 4 waves/SIMD.
// ---------------------------------------------------------------------------
__global__ __launch_bounds__(128, 4) void attn_mfma(const unsigned short* __restrict__ qfb,
                                                    const unsigned short* __restrict__ kfb,
                                                    const unsigned short* __restrict__ vfb,
                                                    const float* __restrict__ frame_bias,
                                                    const int* __restrict__ adj,
                                                    const int* __restrict__ is_hub,
                                                    unsigned short* __restrict__ ath) {
    __shared__ float sM[64][18];      // 4.5 KB merge buffer
    __shared__ int sList[32];
    __shared__ float sFB[8];
    __shared__ unsigned long long sHub[32];
    __shared__ int sNT;

    // XCD decode: bid&7 = XCD, each XCD owns heads {2r, 2r+1}
    const int bid = blockIdx.x;
    const int r8 = bid & 7, tt = bid >> 3;      // tt in [0,256)
    const int q16 = tt & 127, hb = tt >> 7;
    const int h = r8 * 2 + hb;
    const int q0 = q16 * 16;

    const int tid = threadIdx.x;    // 0..127
    const int lane = tid & 63;
    const int w = tid >> 6;         // half 0/1
    const int lr = lane & 15;
    const int kg = lane >> 4;
    const int fi = q0 >> 8;

    // ---- Q fragments: 2 coalesced 16B loads ----
    const unsigned short* qb = qfb + ((size_t)(h * 128 + q16) * 2) * 512;
    bf16x8 qh[2];
    qh[0] = *(const bf16x8*)&qb[lane * 8];
    qh[1] = *(const bf16x8*)&qb[512 + lane * 8];
    const bool hq = is_hub[q0 + lr] != 0;

    // ---- prologue tables ----
#pragma unroll
    for (int i = 0; i < 16; ++i) {
        const int t2 = w * 16 + i;
        unsigned long long mb = __ballot(is_hub[t2 * 64 + lane] != 0);
        if (lane == 0) sHub[t2] = mb;
    }
    if (tid < 8) sFB[tid] = frame_bias[fi * 8 + tid];
    if (w == 0) {
        const bool ok = (lane < 32) && (adj[fi * 8 + ((lane & 31) >> 2)] != 0);
        const unsigned long long am = __ballot(ok);
        if (lane == 0) {
            int c = 0;
#pragma unroll 1
            for (int t2 = 0; t2 < 32; ++t2)
                if ((am >> t2) & 1ull) sList[c++] = t2;
            sNT = c;
        }
    }
    __syncthreads();
    const int nt = sNT;   // >= 4 (adj diagonal)

    const unsigned short* kb = kfb + (size_t)(h * 32) * 4096;
    const unsigned short* vb = vfb + (size_t)(h * 32) * 4096;

    float m_i = -INFINITY, l_i = 0.f;
    f32x4 oacc[4];
#pragma unroll
    for (int fd = 0; fd < 4; ++fd) oacc[fd] = {0.f, 0.f, 0.f, 0.f};

#pragma unroll 1
    for (int i = w; i < nt; i += 2) {
        const int tile = sList[i];
        const size_t tbase = (size_t)tile * 4096 + lane * 8;
        const int fj = tile >> 2;
        const bool same = (fj == fi);
        const float biasv = sFB[fj];
        const unsigned long long hubmask = sHub[tile];

        // ---- K fragments: 8 coalesced 16B loads ----
        bf16x8 kfr[4][2];
#pragma unroll
        for (int fk = 0; fk < 4; ++fk)
#pragma unroll
            for (int dc = 0; dc < 2; ++dc)
                kfr[fk][dc] = *(const bf16x8*)&kb[tbase + (fk * 2 + dc) * 512];

        // ---- S^T = K . Q^T ----
        f32x4 sacc[4];
#pragma unroll
        for (int fk = 0; fk < 4; ++fk) sacc[fk] = {0.f, 0.f, 0.f, 0.f};
        __builtin_amdgcn_s_setprio(1);
#pragma unroll
        for (int fk = 0; fk < 4; ++fk)
#pragma unroll
            for (int dc = 0; dc < 2; ++dc)
                sacc[fk] = __builtin_amdgcn_mfma_f32_16x16x32_bf16(kfr[fk][dc], qh[dc], sacc[fk], 0, 0, 0);
        __builtin_amdgcn_s_setprio(0);

        // ---- V fragments issued now; softmax VALU hides their latency ----
        bf16x8 vfr[2][4];
#pragma unroll
        for (int c = 0; c < 2; ++c)
#pragma unroll
            for (int fd = 0; fd < 4; ++fd)
                vfr[c][fd] = *(const bf16x8*)&vb[tbase + (c * 4 + fd) * 512];

        // ---- mask + bias + online softmax (lane owns 16 scores of its q) ----
        float sv[4][4];
        float rmax = -INFINITY;
#pragma unroll
        for (int fk = 0; fk < 4; ++fk)
#pragma unroll
            for (int r = 0; r < 4; ++r) {
                float val = sacc[fk][r] + biasv;
                if (!same) {
                    const int k = fk * 16 + kg * 4 + r;
                    if (hq || ((hubmask >> k) & 1ull)) val = -INFINITY;
                }
                sv[fk][r] = val;
                rmax = fmaxf(rmax, val);
            }
        rmax = fmaxf(rmax, __shfl_xor(rmax, 16));
        rmax = fmaxf(rmax, __shfl_xor(rmax, 32));

        const float mn = fmaxf(m_i, rmax);
        const float alpha = (mn == -INFINITY) ? 1.f : __expf(m_i - mn);
        m_i = mn;

        float p4[4][4];
        float psum = 0.f;
#pragma unroll
        for (int fk = 0; fk < 4; ++fk)
#pragma unroll
            for (int r = 0; r < 4; ++r) {
                const float pv = (sv[fk][r] == -INFINITY) ? 0.f : __expf(sv[fk][r] - mn);
                p4[fk][r] = pv;
                psum += pv;
            }
        psum += __shfl_xor(psum, 16);
        psum += __shfl_xor(psum, 32);
        l_i = l_i * alpha + psum;
#pragma unroll
        for (int fd = 0; fd < 4; ++fd) {
            oacc[fd][0] *= alpha; oacc[fd][1] *= alpha;
            oacc[fd][2] *= alpha; oacc[fd][3] *= alpha;
        }

        // ---- pack P, O^T += V^T . P^T (k-slot permuted to match vf order) ----
        unsigned int pc[4][2];
#pragma unroll
        for (int fk = 0; fk < 4; ++fk)
#pragma unroll
            for (int rp = 0; rp < 2; ++rp)
                pc[fk][rp] = (unsigned int)bf16_rn(p4[fk][2 * rp]) |
                             ((unsigned int)bf16_rn(p4[fk][2 * rp + 1]) << 16);
        __builtin_amdgcn_s_setprio(1);
#pragma unroll
        for (int c = 0; c < 2; ++c) {
            u32x4 pw = {pc[2 * c][0], pc[2 * c][1], pc[2 * c + 1][0], pc[2 * c + 1][1]};
            bf16x8 pbv = __builtin_bit_cast(bf16x8, pw);
#pragma unroll
            for (int fd = 0; fd < 4; ++fd)
                oacc[fd] = __builtin_amdgcn_mfma_f32_16x16x32_bf16(vfr[c][fd], pbv, oacc[fd], 0, 0, 0);
        }
        __builtin_amdgcn_s_setprio(0);
    }

    // ---- merge the two halves via LDS ----
    if (w == 1) {
        float* mp = &sM[lane][0];
        mp[0] = m_i;
        mp[1] = l_i;
#pragma unroll
        for (int fd = 0; fd < 4; ++fd)
#pragma unroll
            for (int r = 0; r < 4; ++r) mp[2 + fd * 4 + r] = oacc[fd][r];
    }
    __syncthreads();
    if (w == 0) {
        const float mb = sM[lane][0];
        const float lb = sM[lane][1];
        const float m = fmaxf(m_i, mb);
        const float aa = (m_i == -INFINITY) ? 0.f : __expf(m_i - m);
        const float ab = (mb == -INFINITY) ? 0.f : __expf(mb - m);
        const float inv = 1.f / (l_i * aa + lb * ab);
#pragma unroll
        for (int fd = 0; fd < 4; ++fd) {
            ushort4 h4;
            unsigned short hs[4];
#pragma unroll
            for (int r = 0; r < 4; ++r) {
                const float o = (oacc[fd][r] * aa + sM[lane][2 + fd * 4 + r] * ab) * inv;
                hs[r] = bf16_rn(o);
            }
            h4.x = hs[0]; h4.y = hs[1]; h4.z = hs[2]; h4.w = hs[3];
            const size_t idx = (size_t)(q0 + lr) * CDIM + h * 64 + fd * 16 + kg * 4;
            *(ushort4*)&ath[idx] = h4;
        }
    }
}

// ---------------------------------------------------------------------------
extern "C" void kernel_launch(void* const* d_in, const int* in_sizes, int n_in,
                              void* d_out, int out_size, void* d_ws, size_t ws_size,
                              hipStream_t stream) {
    const float* x          = (const float*)d_in[0];
    const float* Wqkv       = (const float*)d_in[1];
    const float* bqkv       = (const float*)d_in[2];
    const float* Wproj      = (const float*)d_in[3];
    const float* bproj      = (const float*)d_in[4];
    const float* frame_bias = (const float*)d_in[5];
    const int*   adj        = (const int*)d_in[6];
    const int*   is_hub     = (const int*)d_in[8];
    float* out = (float*)d_out;

    char* ws = (char*)d_ws;
    size_t off = 0;
    auto alloc_us = [&](size_t n) { unsigned short* p = (unsigned short*)(ws + off); off += n * 2; return p; };
    unsigned short* qfb = alloc_us((size_t)NHEAD * NTOK * HDIM);
    unsigned short* kfb = alloc_us((size_t)NHEAD * NTOK * HDIM);
    unsigned short* vfb = alloc_us((size_t)NHEAD * HDIM * NTOK);
    unsigned short* xh  = alloc_us((size_t)NTOK * CDIM);
    unsigned short* wqh = alloc_us((size_t)3 * CDIM * CDIM);
    unsigned short* wph = alloc_us((size_t)CDIM * CDIM);
    unsigned short* ath = alloc_us((size_t)NTOK * CDIM);

    const int nb_x = (NTOK * CDIM / 4) / 256;
    const int nb_wq = (3 * CDIM * CDIM / 4) / 256;
    const int nb_wp = (CDIM * CDIM / 4) / 256;
    conv3<<<nb_x + nb_wq + nb_wp, 256, 0, stream>>>(x, xh, nb_x,
                                                    Wqkv, wqh, nb_wq,
                                                    Wproj, wph);

    // 1) QKV projection (1-term); epilogue emits fragment-ordered bf16 buffers
    gemm_mfma<64, 128, NTOK, 3 * CDIM, CDIM, 1>
        <<<dim3((3 * CDIM) / 128, NTOK / 64), 256, 0, stream>>>(
            xh, wqh, bqkv, nullptr, qfb, kfb, vfb);
    // 2) sparse attention (fragment-ordered, barrier-free), writes bf16 att
    attn_mfma<<<2048, 128, 0, stream>>>(qfb, kfb, vfb,
                                        frame_bias, adj, is_hub, ath);
    // 3) output projection (1-term, BN=64 -> 512 blocks)
    gemm_mfma<64, 64, NTOK, CDIM, CDIM, 2>
        <<<dim3(CDIM / 64, NTOK / 64), 256, 0, stream>>>(
            ath, wph, bproj, out, nullptr, nullptr, nullptr);
}

// Round 13
// 70.124 us; speedup vs baseline: 1.3748x; 1.0413x over previous
//
#include <hip/hip_runtime.h>
#include <hip/hip_bf16.h>
#include <math.h>

// Problem constants
#define NTOK 2048
#define CDIM 1024
#define NHEAD 16
#define HDIM 64
// frame id = token >> 8 (8 frames of 256 tokens)

typedef __attribute__((ext_vector_type(8))) short bf16x8;
typedef __attribute__((ext_vector_type(4))) float f32x4;
typedef __attribute__((ext_vector_type(4))) unsigned int u32x4;

// ---------------------------------------------------------------------------
// helpers
// ---------------------------------------------------------------------------
__device__ inline unsigned short bf16_rn(float f) {
    unsigned int u = __float_as_uint(f);
    u += 0x7FFFu + ((u >> 16) & 1u);
    return (unsigned short)(u >> 16);
}

template <int N> __device__ inline void waitcnt_vm() {
    if constexpr (N == 0) asm volatile("s_waitcnt vmcnt(0)" ::: "memory");
    else if constexpr (N == 4) asm volatile("s_waitcnt vmcnt(4)" ::: "memory");
    else if constexpr (N == 6) asm volatile("s_waitcnt vmcnt(6)" ::: "memory");
}

__device__ inline void gload16(const void* g, void* l) {
    __builtin_amdgcn_global_load_lds((const __attribute__((address_space(1))) void*)g,
                                     (__attribute__((address_space(3))) void*)l,
                                     16, 0, 0);
}

// One dispatch: convert x, Wqkv, Wproj to plain bf16.
__global__ __launch_bounds__(256) void conv3(const float* __restrict__ s0, unsigned short* __restrict__ h0, int nb0,
                                             const float* __restrict__ s1, unsigned short* __restrict__ h1, int nb1,
                                             const float* __restrict__ s2, unsigned short* __restrict__ h2) {
    int b = blockIdx.x;
    const float* s;
    unsigned short* hh;
    if (b < nb0) { s = s0; hh = h0; }
    else if (b < nb0 + nb1) { s = s1; hh = h1; b -= nb0; }
    else { s = s2; hh = h2; b -= nb0 + nb1; }
    const int i = b * 256 + threadIdx.x;
    float4 v = ((const float4*)s)[i];
    ushort4 h;
    h.x = bf16_rn(v.x); h.y = bf16_rn(v.y); h.z = bf16_rn(v.z); h.w = bf16_rn(v.w);
    ((ushort4*)hh)[i] = h;
}

// ---------------------------------------------------------------------------
// MFMA GEMM, 1-term bf16, BK=64 (16 MFMA per wave per phase), counted-vmcnt
// double buffer. 4 waves (2x2).
// MODE 1 (QKV): epilogue writes attention FRAGMENT-ORDERED bf16 buffers:
//   qf[h][q16][dc][lane][8]   (scaled 0.125)   lane = kg*16 + (tok&15)
//   kf[h][tile][fk][dc][lane][8]
//   vf[h][tile][c][fd][lane][8]                (element order matches PV A-op)
// MODE 2 (PROJ): f32 out + bias.
// ---------------------------------------------------------------------------
template <int BM, int BN, int M, int N, int K, int MODE>
__global__ __launch_bounds__(256) void gemm_mfma(const unsigned short* __restrict__ Ah,
                                                 const unsigned short* __restrict__ Bh,
                                                 const float* __restrict__ bias,
                                                 float* __restrict__ C,
                                                 unsigned short* __restrict__ qfb,
                                                 unsigned short* __restrict__ kfb,
                                                 unsigned short* __restrict__ vfb) {
    constexpr int BK = 64;
    constexpr int FM = BM / 32;
    constexpr int FN = BN / 32;
    constexpr int ASZ = BM * BK;
    constexpr int BSZ = BN * BK;
    constexpr int BUF = ASZ + BSZ;
    __shared__ unsigned short lds[2 * BUF];

    const int tid = threadIdx.x;
    const int lane = tid & 63;
    const int w = tid >> 6;
    const int m0 = blockIdx.y * BM;
    const int n0 = blockIdx.x * BN;
    const int wave_m = (w >> 1) * (BM / 2);
    const int wave_n = (w & 1) * (BN / 2);
    const int lr = lane & 15;
    const int kg_ = lane >> 4;
    const int srow = tid >> 3;          // 0..31
    const int scol = (tid & 7) * 8;     // bf16 elems within 64-col row

    const size_t aRow = (size_t)(m0 + srow) * K + scol;
    const size_t bRow = (size_t)(n0 + srow) * K + scol;

    f32x4 acc[FM][FN];
#pragma unroll
    for (int i = 0; i < FM; ++i)
#pragma unroll
        for (int j = 0; j < FN; ++j) acc[i][j] = {0.f, 0.f, 0.f, 0.f};

    auto stage = [&](int buf, int k0) {
        unsigned short* bb = lds + buf * BUF;
#pragma unroll
        for (int j = 0; j < BM / 32; ++j)
            gload16(Ah + aRow + (size_t)j * 32 * K + k0, bb + (srow + j * 32) * BK + scol);
#pragma unroll
        for (int j = 0; j < BN / 32; ++j)
            gload16(Bh + bRow + (size_t)j * 32 * K + k0, bb + ASZ + (srow + j * 32) * BK + scol);
    };

    stage(0, 0);
    constexpr int NL = BM / 32 + BN / 32;
    constexpr int NT = K / BK;
    for (int t = 0; t < NT; ++t) {
        const int cur = t & 1;
        if (t + 1 < NT) {
            stage(cur ^ 1, (t + 1) * BK);
            waitcnt_vm<NL>();   // own current-phase loads done; next in flight
        } else {
            waitcnt_vm<0>();
        }
        __builtin_amdgcn_s_barrier();

        const unsigned short* bb = lds + cur * BUF;
        bf16x8 ah[FM][2], bh[FN][2];
#pragma unroll
        for (int f = 0; f < FM; ++f)
#pragma unroll
            for (int ks = 0; ks < 2; ++ks)
                ah[f][ks] = *(const bf16x8*)&bb[(wave_m + f * 16 + lr) * BK + ks * 32 + kg_ * 8];
#pragma unroll
        for (int f = 0; f < FN; ++f)
#pragma unroll
            for (int ks = 0; ks < 2; ++ks)
                bh[f][ks] = *(const bf16x8*)&bb[ASZ + (wave_n + f * 16 + lr) * BK + ks * 32 + kg_ * 8];
        __builtin_amdgcn_s_setprio(1);
#pragma unroll
        for (int ks = 0; ks < 2; ++ks)
#pragma unroll
            for (int fm = 0; fm < FM; ++fm)
#pragma unroll
                for (int fn = 0; fn < FN; ++fn)
                    acc[fm][fn] = __builtin_amdgcn_mfma_f32_16x16x32_bf16(ah[fm][ks], bh[fn][ks], acc[fm][fn], 0, 0, 0);
        __builtin_amdgcn_s_setprio(0);
        asm volatile("" ::: "memory");
        __builtin_amdgcn_s_barrier();
    }

    // epilogue: C/D layout col=lane&15, row=(lane>>4)*4+reg  [m89-verified]
    if constexpr (MODE == 2) {
        float bv[FN];
#pragma unroll
        for (int fn = 0; fn < FN; ++fn) bv[fn] = bias[n0 + wave_n + fn * 16 + lr];
#pragma unroll
        for (int fm = 0; fm < FM; ++fm) {
            const int row0 = m0 + wave_m + fm * 16 + kg_ * 4;
#pragma unroll
            for (int fn = 0; fn < FN; ++fn) {
                const int col = n0 + wave_n + fn * 16 + lr;
#pragma unroll
                for (int r = 0; r < 4; ++r)
                    C[(size_t)(row0 + r) * N + col] = acc[fm][fn][r] + bv[fn];
            }
        }
    } else {
        const int reg = n0 >> 10;  // 0=q, 1=k, 2=v (uniform per block)
#pragma unroll
        for (int fn = 0; fn < FN; ++fn) {
            const int col = n0 + wave_n + fn * 16 + lr;
            const int head = (col >> 6) & 15;
            const int d = col & 63;
            const float bv = bias[col];
#pragma unroll
            for (int fm = 0; fm < FM; ++fm) {
                const int row0 = m0 + wave_m + fm * 16 + kg_ * 4;  // tok base (mult of 4)
                if (reg == 2) {
                    // vf[h][tile][c][fd][lane][8]; tok&3 == e-low -> ushort4 at e=hi*4
                    const int tok = row0;
                    const int tile = tok >> 6;
                    const int t6 = tok & 63;
                    const int c = t6 >> 5;
                    const int t5 = t6 & 31;
                    const int hi = (t5 >> 4) & 1;
                    const int kgv = (t5 >> 2) & 3;
                    const int fd = d >> 4;
                    const int lrv = d & 15;
                    ushort4 pk;
                    pk.x = bf16_rn(acc[fm][fn][0] + bv);
                    pk.y = bf16_rn(acc[fm][fn][1] + bv);
                    pk.z = bf16_rn(acc[fm][fn][2] + bv);
                    pk.w = bf16_rn(acc[fm][fn][3] + bv);
                    const size_t idx = (((size_t)((head * 32 + tile) * 2 + c) * 4 + fd) * 64 +
                                        (kgv * 16 + lrv)) * 8 + hi * 4;
                    *(ushort4*)&vfb[idx] = pk;
                } else if (reg == 1) {
                    // kf[h][tile][fk][dc][lane][8]
                    const int dc = d >> 5;
                    const int kgq = (d >> 3) & 3;
                    const int e = d & 7;
#pragma unroll
                    for (int r = 0; r < 4; ++r) {
                        const int tok = row0 + r;
                        const int tile = tok >> 6;
                        const int fk = (tok >> 4) & 3;
                        const int lrk = tok & 15;
                        const size_t idx = (((size_t)((head * 32 + tile) * 4 + fk) * 2 + dc) * 64 +
                                            (kgq * 16 + lrk)) * 8 + e;
                        kfb[idx] = bf16_rn(acc[fm][fn][r] + bv);
                    }
                } else {
                    // qf[h][q16][dc][lane][8], scaled 0.125
                    const int dc = d >> 5;
                    const int kgq = (d >> 3) & 3;
                    const int e = d & 7;
#pragma unroll
                    for (int r = 0; r < 4; ++r) {
                        const int tok = row0 + r;
                        const int q16i = tok >> 4;
                        const int lrk = tok & 15;
                        const size_t idx = (((size_t)(head * 128 + q16i) * 2 + dc) * 64 +
                                            (kgq * 16 + lrk)) * 8 + e;
                        qfb[idx] = bf16_rn((acc[fm][fn][r] + bv) * 0.125f);
                    }
                }
            }
        }
    }
}

// ---------------------------------------------------------------------------
// MFMA sparse flash attention — fragment-ordered global K/V/Q, coalesced
// direct loads, no LDS staging, no barriers in the loop, defer-max (THR=8).
// Block = 128 threads = 2 waves = the two KV-halves of one (head, 16-q group).
// ---------------------------------------------------------------------------
__global__ __launch_bounds__(128, 4) void attn_mfma(const unsigned short* __restrict__ qfb,
                                                    const unsigned short* __restrict__ kfb,
                                                    const unsigned short* __restrict__ vfb,
                                                    const float* __restrict__ frame_bias,
                                                    const int* __restrict__ adj,
                                                    const int* __restrict__ is_hub,
                                                    unsigned short* __restrict__ ath) {
    __shared__ float sM[64][18];      // 4.5 KB merge buffer
    __shared__ int sList[32];
    __shared__ float sFB[8];
    __shared__ unsigned long long sHub[32];
    __shared__ int sNT;

    // XCD decode: bid&7 = XCD, each XCD owns heads {2r, 2r+1}
    const int bid = blockIdx.x;
    const int r8 = bid & 7, tt = bid >> 3;      // tt in [0,256)
    const int q16 = tt & 127, hb = tt >> 7;
    const int h = r8 * 2 + hb;
    const int q0 = q16 * 16;

    const int tid = threadIdx.x;    // 0..127
    const int lane = tid & 63;
    const int w = tid >> 6;         // half 0/1
    const int lr = lane & 15;
    const int kg = lane >> 4;
    const int fi = q0 >> 8;

    // ---- Q fragments: 2 coalesced 16B loads ----
    const unsigned short* qb = qfb + ((size_t)(h * 128 + q16) * 2) * 512;
    bf16x8 qh[2];
    qh[0] = *(const bf16x8*)&qb[lane * 8];
    qh[1] = *(const bf16x8*)&qb[512 + lane * 8];
    const bool hq = is_hub[q0 + lr] != 0;

    // ---- prologue tables ----
#pragma unroll
    for (int i = 0; i < 16; ++i) {
        const int t2 = w * 16 + i;
        unsigned long long mb = __ballot(is_hub[t2 * 64 + lane] != 0);
        if (lane == 0) sHub[t2] = mb;
    }
    if (tid < 8) sFB[tid] = frame_bias[fi * 8 + tid];
    if (w == 0) {
        const bool ok = (lane < 32) && (adj[fi * 8 + ((lane & 31) >> 2)] != 0);
        const unsigned long long am = __ballot(ok);
        if (lane == 0) {
            int c = 0;
#pragma unroll 1
            for (int t2 = 0; t2 < 32; ++t2)
                if ((am >> t2) & 1ull) sList[c++] = t2;
            sNT = c;
        }
    }
    __syncthreads();
    const int nt = sNT;   // >= 4 (adj diagonal)

    const unsigned short* kb = kfb + (size_t)(h * 32) * 4096;
    const unsigned short* vb = vfb + (size_t)(h * 32) * 4096;

    float m_i = -INFINITY, l_i = 0.f;
    f32x4 oacc[4];
#pragma unroll
    for (int fd = 0; fd < 4; ++fd) oacc[fd] = {0.f, 0.f, 0.f, 0.f};

#pragma unroll 1
    for (int i = w; i < nt; i += 2) {
        const int tile = sList[i];
        const size_t tbase = (size_t)tile * 4096 + lane * 8;
        const int fj = tile >> 2;
        const bool same = (fj == fi);
        const float biasv = sFB[fj];
        const unsigned long long hubmask = sHub[tile];

        // ---- K fragments: 8 coalesced 16B loads ----
        bf16x8 kfr[4][2];
#pragma unroll
        for (int fk = 0; fk < 4; ++fk)
#pragma unroll
            for (int dc = 0; dc < 2; ++dc)
                kfr[fk][dc] = *(const bf16x8*)&kb[tbase + (fk * 2 + dc) * 512];

        // ---- S^T = K . Q^T ----
        f32x4 sacc[4];
#pragma unroll
        for (int fk = 0; fk < 4; ++fk) sacc[fk] = {0.f, 0.f, 0.f, 0.f};
        __builtin_amdgcn_s_setprio(1);
#pragma unroll
        for (int fk = 0; fk < 4; ++fk)
#pragma unroll
            for (int dc = 0; dc < 2; ++dc)
                sacc[fk] = __builtin_amdgcn_mfma_f32_16x16x32_bf16(kfr[fk][dc], qh[dc], sacc[fk], 0, 0, 0);
        __builtin_amdgcn_s_setprio(0);

        // ---- V fragments issued now; softmax VALU hides their latency ----
        bf16x8 vfr[2][4];
#pragma unroll
        for (int c = 0; c < 2; ++c)
#pragma unroll
            for (int fd = 0; fd < 4; ++fd)
                vfr[c][fd] = *(const bf16x8*)&vb[tbase + (c * 4 + fd) * 512];

        // ---- mask + bias + online softmax with defer-max (THR=8) ----
        float sv[4][4];
        float rmax = -INFINITY;
#pragma unroll
        for (int fk = 0; fk < 4; ++fk)
#pragma unroll
            for (int r = 0; r < 4; ++r) {
                float val = sacc[fk][r] + biasv;
                if (!same) {
                    const int k = fk * 16 + kg * 4 + r;
                    if (hq || ((hubmask >> k) & 1ull)) val = -INFINITY;
                }
                sv[fk][r] = val;
                rmax = fmaxf(rmax, val);
            }
        rmax = fmaxf(rmax, __shfl_xor(rmax, 16));
        rmax = fmaxf(rmax, __shfl_xor(rmax, 32));

        if (!__all(rmax <= m_i + 8.f)) {      // rescale only on real max growth
            const float mn = fmaxf(m_i, rmax);
            const float alpha = (m_i == -INFINITY) ? 0.f : __expf(m_i - mn);
            m_i = mn;
            l_i *= alpha;
#pragma unroll
            for (int fd = 0; fd < 4; ++fd) {
                oacc[fd][0] *= alpha; oacc[fd][1] *= alpha;
                oacc[fd][2] *= alpha; oacc[fd][3] *= alpha;
            }
        }

        float p4[4][4];
        float psum = 0.f;
#pragma unroll
        for (int fk = 0; fk < 4; ++fk)
#pragma unroll
            for (int r = 0; r < 4; ++r) {
                const float pv = (sv[fk][r] == -INFINITY) ? 0.f : __expf(sv[fk][r] - m_i);
                p4[fk][r] = pv;
                psum += pv;
            }
        psum += __shfl_xor(psum, 16);
        psum += __shfl_xor(psum, 32);
        l_i += psum;

        // ---- pack P, O^T += V^T . P^T (k-slot permuted to match vf order) ----
        unsigned int pc[4][2];
#pragma unroll
        for (int fk = 0; fk < 4; ++fk)
#pragma unroll
            for (int rp = 0; rp < 2; ++rp)
                pc[fk][rp] = (unsigned int)bf16_rn(p4[fk][2 * rp]) |
                             ((unsigned int)bf16_rn(p4[fk][2 * rp + 1]) << 16);
        __builtin_amdgcn_s_setprio(1);
#pragma unroll
        for (int c = 0; c < 2; ++c) {
            u32x4 pw = {pc[2 * c][0], pc[2 * c][1], pc[2 * c + 1][0], pc[2 * c + 1][1]};
            bf16x8 pbv = __builtin_bit_cast(bf16x8, pw);
#pragma unroll
            for (int fd = 0; fd < 4; ++fd)
                oacc[fd] = __builtin_amdgcn_mfma_f32_16x16x32_bf16(vfr[c][fd], pbv, oacc[fd], 0, 0, 0);
        }
        __builtin_amdgcn_s_setprio(0);
    }

    // ---- merge the two halves via LDS ----
    if (w == 1) {
        float* mp = &sM[lane][0];
        mp[0] = m_i;
        mp[1] = l_i;
#pragma unroll
        for (int fd = 0; fd < 4; ++fd)
#pragma unroll
            for (int r = 0; r < 4; ++r) mp[2 + fd * 4 + r] = oacc[fd][r];
    }
    __syncthreads();
    if (w == 0) {
        const float mb = sM[lane][0];
        const float lb = sM[lane][1];
        const float m = fmaxf(m_i, mb);
        const float aa = (m_i == -INFINITY) ? 0.f : __expf(m_i - m);
        const float ab = (mb == -INFINITY) ? 0.f : __expf(mb - m);
        const float inv = 1.f / (l_i * aa + lb * ab);
#pragma unroll
        for (int fd = 0; fd < 4; ++fd) {
            ushort4 h4;
            unsigned short hs[4];
#pragma unroll
            for (int r = 0; r < 4; ++r) {
                const float o = (oacc[fd][r] * aa + sM[lane][2 + fd * 4 + r] * ab) * inv;
                hs[r] = bf16_rn(o);
            }
            h4.x = hs[0]; h4.y = hs[1]; h4.z = hs[2]; h4.w = hs[3];
            const size_t idx = (size_t)(q0 + lr) * CDIM + h * 64 + fd * 16 + kg * 4;
            *(ushort4*)&ath[idx] = h4;
        }
    }
}

// ---------------------------------------------------------------------------
extern "C" void kernel_launch(void* const* d_in, const int* in_sizes, int n_in,
                              void* d_out, int out_size, void* d_ws, size_t ws_size,
                              hipStream_t stream) {
    const float* x          = (const float*)d_in[0];
    const float* Wqkv       = (const float*)d_in[1];
    const float* bqkv       = (const float*)d_in[2];
    const float* Wproj      = (const float*)d_in[3];
    const float* bproj      = (const float*)d_in[4];
    const float* frame_bias = (const float*)d_in[5];
    const int*   adj        = (const int*)d_in[6];
    const int*   is_hub     = (const int*)d_in[8];
    float* out = (float*)d_out;

    char* ws = (char*)d_ws;
    size_t off = 0;
    auto alloc_us = [&](size_t n) { unsigned short* p = (unsigned short*)(ws + off); off += n * 2; return p; };
    unsigned short* qfb = alloc_us((size_t)NHEAD * NTOK * HDIM);
    unsigned short* kfb = alloc_us((size_t)NHEAD * NTOK * HDIM);
    unsigned short* vfb = alloc_us((size_t)NHEAD * HDIM * NTOK);
    unsigned short* xh  = alloc_us((size_t)NTOK * CDIM);
    unsigned short* wqh = alloc_us((size_t)3 * CDIM * CDIM);
    unsigned short* wph = alloc_us((size_t)CDIM * CDIM);
    unsigned short* ath = alloc_us((size_t)NTOK * CDIM);

    const int nb_x = (NTOK * CDIM / 4) / 256;
    const int nb_wq = (3 * CDIM * CDIM / 4) / 256;
    const int nb_wp = (CDIM * CDIM / 4) / 256;
    conv3<<<nb_x + nb_wq + nb_wp, 256, 0, stream>>>(x, xh, nb_x,
                                                    Wqkv, wqh, nb_wq,
                                                    Wproj, wph);

    // 1) QKV projection (1-term, BK=64); epilogue emits fragment-ordered bf16
    gemm_mfma<64, 128, NTOK, 3 * CDIM, CDIM, 1>
        <<<dim3((3 * CDIM) / 128, NTOK / 64), 256, 0, stream>>>(
            xh, wqh, bqkv, nullptr, qfb, kfb, vfb);
    // 2) sparse attention (fragment-ordered, barrier-free, defer-max)
    attn_mfma<<<2048, 128, 0, stream>>>(qfb, kfb, vfb,
                                        frame_bias, adj, is_hub, ath);
    // 3) output projection (1-term, BK=64, BN=64 -> 512 blocks)
    gemm_mfma<64, 64, NTOK, CDIM, CDIM, 2>
        <<<dim3(CDIM / 64, NTOK / 64), 256, 0, stream>>>(
            ath, wph, bproj, out, nullptr, nullptr, nullptr);
}